// Round 14
// baseline (1004.280 us; speedup 1.0000x reference)
//
#include <hip/hip_runtime.h>

// MoE feed-forward, top-2 of 8 experts. T=4096, D=2048, H=4096, E=8, fp32 io.
// Round 14: round-13 structure; gemm2b split-K x2 -> x4 (1024 active blocks,
// 4 slots/CU), 4 disjoint partial buffers, combine sums 4 partials.
// Everything else identical to round 13 (best measured, 978us).
//
// ws layout:
//   [0,32) counts  [32,64) cursor  [64,96) offsets
//   [128,+32K) sel[T][2]   [32896,..) cw[T][2]
//   [65664,..) pair_token[8192]  [98432,..) pair_cw[8192]
//   [131200,..) tpair[T][2]
//   [256K, +64MB)  hbuf bf16 [8192][H]
//   [68MB, +16MB)  xb  bf16 [T][D]
//   [96MB,+64MB each) ybuf0..3 f32 [8192][D] (overlay w1b/w3b, dead after gemm1)
//   [96MB, +128MB) w1b bf16 [E][H][D]
//   [224MB,+128MB) w3b bf16 [E][H][D]
//   [352MB,+128MB) w2b bf16 [E][D][H]
// fast path needs 480MB; falls back to round-1 fp32-load path otherwise.

#define NT 4096
#define ND 2048
#define NH 4096
#define NE 8

typedef __bf16 bf16;
typedef __attribute__((ext_vector_type(4))) __bf16 bf16x4;
typedef __attribute__((ext_vector_type(8))) __bf16 bf16x8;
typedef __attribute__((ext_vector_type(4))) float f32x4;

__device__ __forceinline__ void gload16(const void* g, void* l) {
    __builtin_amdgcn_global_load_lds(
        (const __attribute__((address_space(1))) void*)g,
        (__attribute__((address_space(3))) void*)l, 16, 0, 0);
}

// ---------------- router: logits -> top2 -> renorm; emits bf16 x ----------------
__global__ __launch_bounds__(64) void router_kernel(
    const float* __restrict__ x, const float* __restrict__ rweights,
    int* __restrict__ counts, int* __restrict__ sel, float* __restrict__ cw,
    bf16* __restrict__ xb)
{
    const int t = blockIdx.x;
    const int lane = threadIdx.x;
    float acc[NE];
#pragma unroll
    for (int e = 0; e < NE; ++e) acc[e] = 0.f;
    const float* xr = x + (size_t)t * ND;
#pragma unroll
    for (int i = 0; i < ND / 256; ++i) {          // 8 iters of float4
        const int d4 = i * 64 + lane;
        const float4 xv = ((const float4*)xr)[d4];
        if (xb != nullptr) {
            bf16x4 v = {(bf16)xv.x, (bf16)xv.y, (bf16)xv.z, (bf16)xv.w};
            *(bf16x4*)(xb + (size_t)t * ND + d4 * 4) = v;
        }
#pragma unroll
        for (int e = 0; e < NE; ++e) {
            const float4 wv = ((const float4*)(rweights + e * ND))[d4];
            acc[e] += xv.x * wv.x + xv.y * wv.y + xv.z * wv.z + xv.w * wv.w;
        }
    }
#pragma unroll
    for (int e = 0; e < NE; ++e) {
#pragma unroll
        for (int off = 32; off > 0; off >>= 1)
            acc[e] += __shfl_xor(acc[e], off);
    }
    if (lane == 0) {
        int e0 = 0;
#pragma unroll
        for (int e = 1; e < NE; ++e) if (acc[e] > acc[e0]) e0 = e;
        int e1 = (e0 == 0) ? 1 : 0;
#pragma unroll
        for (int e = 0; e < NE; ++e) if (e != e0 && acc[e] > acc[e1]) e1 = e;
        const float w0 = 1.f / (1.f + expf(acc[e1] - acc[e0]));
        sel[t * 2 + 0] = e0; sel[t * 2 + 1] = e1;
        cw[t * 2 + 0] = w0;  cw[t * 2 + 1] = 1.f - w0;
        atomicAdd(&counts[e0], 1);
        atomicAdd(&counts[e1], 1);
    }
}

__global__ void prefix_kernel(int* __restrict__ counts, int* __restrict__ cursor,
                              int* __restrict__ offsets)
{
    int s = 0;
    for (int e = 0; e < NE; ++e) { offsets[e] = s; s += counts[e]; cursor[e] = 0; }
}

__global__ __launch_bounds__(256) void scatter_kernel(
    const int* __restrict__ sel, const float* __restrict__ cw,
    const int* __restrict__ offsets, int* __restrict__ cursor,
    int* __restrict__ ptok, float* __restrict__ pcw, int* __restrict__ tpair)
{
    const int t = blockIdx.x * 256 + threadIdx.x;
    if (t >= NT) return;
#pragma unroll
    for (int k = 0; k < 2; ++k) {
        const int e = sel[t * 2 + k];
        const int pos = atomicAdd(&cursor[e], 1);
        const int idx = offsets[e] + pos;
        ptok[idx] = t;
        pcw[idx] = cw[t * 2 + k];
        tpair[t * 2 + k] = idx;
    }
}

// ---------------- fp32 -> bf16 conversion for w1,w3 only ----------------
__global__ __launch_bounds__(256) void cvt13_kernel(
    const float* __restrict__ w1, bf16* __restrict__ w1b,
    const float* __restrict__ w3, bf16* __restrict__ w3b)
{
    const int nw = NE * NH * ND / 8;
    const int total = 2 * nw;
    for (int i = blockIdx.x * 256 + threadIdx.x; i < total; i += gridDim.x * 256) {
        const float* s; bf16* d; int j;
        if (i < nw) { s = w1; d = w1b; j = i; }
        else        { s = w3; d = w3b; j = i - nw; }
        const float4 a = ((const float4*)s)[2 * (size_t)j];
        const float4 b = ((const float4*)s)[2 * (size_t)j + 1];
        bf16x8 v = {(bf16)a.x, (bf16)a.y, (bf16)a.z, (bf16)a.w,
                    (bf16)b.x, (bf16)b.y, (bf16)b.z, (bf16)b.w};
        *(bf16x8*)(d + 8 * (size_t)j) = v;
    }
}

// ---------------- combine: out[t] = sum_k cw_k * sum_s ys[p_k] ----------------
__global__ __launch_bounds__(256) void combine_kernel(
    const float* __restrict__ y0, const float* __restrict__ y1,
    const float* __restrict__ y2, const float* __restrict__ y3,
    const int* __restrict__ tpair, const float* __restrict__ cw,
    float* __restrict__ out)
{
    const int total = NT * ND / 4;
    for (int i = blockIdx.x * 256 + threadIdx.x; i < total; i += gridDim.x * 256) {
        const int t = i >> 9;            // ND/4 = 512 float4 per token
        const int c = i & 511;
        const int p0 = tpair[t * 2 + 0], p1 = tpair[t * 2 + 1];
        const float w0 = cw[t * 2 + 0], w1 = cw[t * 2 + 1];
        const size_t o0 = (size_t)p0 * ND, o1 = (size_t)p1 * ND;
        const float4 a0 = ((const float4*)(y0 + o0))[c];
        const float4 a1 = ((const float4*)(y1 + o0))[c];
        const float4 a2 = ((const float4*)(y2 + o0))[c];
        const float4 a3 = ((const float4*)(y3 + o0))[c];
        const float4 b0 = ((const float4*)(y0 + o1))[c];
        const float4 b1 = ((const float4*)(y1 + o1))[c];
        const float4 b2 = ((const float4*)(y2 + o1))[c];
        const float4 b3 = ((const float4*)(y3 + o1))[c];
        float4 o;
        o.x = w0 * (a0.x + a1.x + a2.x + a3.x) + w1 * (b0.x + b1.x + b2.x + b3.x);
        o.y = w0 * (a0.y + a1.y + a2.y + a3.y) + w1 * (b0.y + b1.y + b2.y + b3.y);
        o.z = w0 * (a0.z + a1.z + a2.z + a3.z) + w1 * (b0.z + b1.z + b2.z + b3.z);
        o.w = w0 * (a0.w + a1.w + a2.w + a3.w) + w1 * (b0.w + b1.w + b2.w + b3.w);
        ((float4*)(out + (size_t)t * ND))[c] = o;
    }
}

// ========== FAST PATH gemm1b: round-8 exact (counted-vmcnt depth-2 + w2 cvt) ==========
// LDS content(row, granule gg) = global[row][gg ^ (row&7)]; reads use
// granule (k_granule ^ (row&7)) — swizzle pair verified rounds 1-13.

__global__ __launch_bounds__(512, 2) void gemm1b_kernel(
    const bf16* __restrict__ xb, const bf16* __restrict__ w1b,
    const bf16* __restrict__ w3b, const int* __restrict__ counts,
    const int* __restrict__ offsets, const int* __restrict__ ptok,
    bf16* __restrict__ hbuf,
    const float* __restrict__ w2, bf16* __restrict__ w2b)
{
    const int bid = blockIdx.x;
    const int tid = threadIdx.x;

    if (bid >= 4096) {
        // w2 conversion role: 1024 blocks x 512 threads, 16 float8 each
        const int idx = (bid - 4096) * 512 + tid;
#pragma unroll
        for (int j = 0; j < 16; ++j) {
            const size_t i = (size_t)idx + (size_t)j * (1024 * 512);
            const float4 a = ((const float4*)w2)[2 * i];
            const float4 b = ((const float4*)w2)[2 * i + 1];
            bf16x8 v = {(bf16)a.x, (bf16)a.y, (bf16)a.z, (bf16)a.w,
                        (bf16)b.x, (bf16)b.y, (bf16)b.z, (bf16)b.w};
            *(bf16x8*)(w2b + 8 * i) = v;
        }
        return;
    }

    // decode: xcd = bid&7 gets ntile group [4*xcd, 4*xcd+4) for ALL (e,mtile)
    const int xcd = bid & 7;
    const int s = bid >> 3;                  // 0..511
    const int ntile = xcd * 4 + (s & 3);     // 0..31
    const int em = s >> 2;                   // 0..127
    const int mtile = em & 15;
    const int e = em >> 4;

    const int ne = counts[e];
    if (mtile * 256 >= ne) return;
    const int off = offsets[e];
    const int lane = tid & 63;
    const int wid = tid >> 6;
    const int waveM = wid >> 1, waveN = wid & 1;   // 4M x 2N wave grid

    __shared__ alignas(16) bf16 As[2][256 * 64];   // 64KB
    __shared__ alignas(16) bf16 B1s[2][128 * 64];  // 32KB
    __shared__ alignas(16) bf16 B3s[2][128 * 64];  // 32KB

    const int gg = tid & 7;
    const int r0 = tid >> 3;                 // 0..63
    const int sgg = gg ^ (r0 & 7);           // pre-swizzled SOURCE granule

    const char* asrc[4];
#pragma unroll
    for (int i = 0; i < 4; ++i) {
        const int rg = mtile * 256 + i * 64 + r0;
        const int rc = rg < ne ? rg : ne - 1;
        const int tok = ptok[off + rc];
        asrc[i] = (const char*)(xb + (size_t)tok * ND) + sgg * 16;
    }
    const char* b1src = (const char*)(w1b + (size_t)e * NH * ND
                        + (size_t)(ntile * 128 + r0) * ND) + sgg * 16;
    const char* b3src = (const char*)(w3b + (size_t)e * NH * ND
                        + (size_t)(ntile * 128 + r0) * ND) + sgg * 16;
    const size_t bstep = (size_t)64 * ND * 2;

    f32x4 accG[4][4], accU[4][4];
#pragma unroll
    for (int i = 0; i < 4; ++i)
#pragma unroll
        for (int j = 0; j < 4; ++j) { accG[i][j] = (f32x4)0.f; accU[i][j] = (f32x4)0.f; }

    const int hi = lane >> 4, lo = lane & 15;

    auto stage = [&](int b, int kt) {   // 8 global_load_lds_dwordx4 per thread
        const int kb = kt * 128;
        char* ad  = (char*)&As[b][0]  + tid * 16;
        char* b1d = (char*)&B1s[b][0] + tid * 16;
        char* b3d = (char*)&B3s[b][0] + tid * 16;
#pragma unroll
        for (int i = 0; i < 4; ++i) gload16(asrc[i] + kb, ad + i * 8192);
#pragma unroll
        for (int i = 0; i < 2; ++i) gload16(b1src + i * bstep + kb, b1d + i * 8192);
#pragma unroll
        for (int i = 0; i < 2; ++i) gload16(b3src + i * bstep + kb, b3d + i * 8192);
    };

    stage(0, 0);
    int cur = 0;
    const int NK = ND / 64;
    for (int kt = 0; kt < NK; ++kt) {
        if (kt + 1 < NK) {
            stage(cur ^ 1, kt + 1);   // prefetch next K-tile (stays in flight)
            asm volatile("s_waitcnt vmcnt(8)" ::: "memory");  // tile kt landed
        } else {
            asm volatile("s_waitcnt vmcnt(0)" ::: "memory");
        }
        __builtin_amdgcn_s_barrier();
        __builtin_amdgcn_sched_barrier(0);
        const char* Ab  = (const char*)&As[cur][0];
        const char* B1b = (const char*)&B1s[cur][0];
        const char* B3b = (const char*)&B3s[cur][0];
#pragma unroll
        for (int kk = 0; kk < 2; ++kk) {
            bf16x8 a[4], bg[4], bu[4];
            const int g = ((kk * 4 + hi) ^ (lo & 7)) * 16;
#pragma unroll
            for (int i = 0; i < 4; ++i) {
                a[i]  = *(const bf16x8*)(Ab  + (waveM * 64 + i * 16 + lo) * 128 + g);
                bg[i] = *(const bf16x8*)(B1b + (waveN * 64 + i * 16 + lo) * 128 + g);
                bu[i] = *(const bf16x8*)(B3b + (waveN * 64 + i * 16 + lo) * 128 + g);
            }
#pragma unroll
            for (int mi = 0; mi < 4; ++mi)
#pragma unroll
                for (int ni = 0; ni < 4; ++ni) {
                    accG[mi][ni] = __builtin_amdgcn_mfma_f32_16x16x32_bf16(a[mi], bg[ni], accG[mi][ni], 0, 0, 0);
                    accU[mi][ni] = __builtin_amdgcn_mfma_f32_16x16x32_bf16(a[mi], bu[ni], accU[mi][ni], 0, 0, 0);
                }
        }
        __builtin_amdgcn_sched_barrier(0);
        asm volatile("" ::: "memory");
        __builtin_amdgcn_s_barrier();     // all waves done reading buf[cur]
        cur ^= 1;
    }

    // epilogue: h = silu(gate)*up -> bf16 hbuf[pair][H]
#pragma unroll
    for (int mi = 0; mi < 4; ++mi) {
#pragma unroll
        for (int r = 0; r < 4; ++r) {
            const int rowg = mtile * 256 + waveM * 64 + mi * 16 + hi * 4 + r;
            if (rowg < ne) {
                const size_t p = (size_t)(off + rowg);
                bf16* hrow = hbuf + p * NH + ntile * 128 + waveN * 64 + lo;
#pragma unroll
                for (int ni = 0; ni < 4; ++ni) {
                    const float gv = accG[mi][ni][r];
                    const float uv = accU[mi][ni][r];
                    const float h = (gv / (1.f + __expf(-gv))) * uv;
                    hrow[ni * 16] = (bf16)h;
                }
            }
        }
    }
}

// gemm2b: 256x256 tile, 8 waves 2Mx4N, round-8 schedule, SPLIT-K x4:
// each block computes K-quarter ks (1024 wide, NK=16), writes partial to
// ybuf[ks]. 4096 blocks declared, 1024 active -> 4 slots/CU.
// XCD decode: xcd = (mtile + e) & 7 keeps A-panel sharers on one XCD.
__global__ __launch_bounds__(512, 2) void gemm2b_kernel(
    const bf16* __restrict__ hbuf, const bf16* __restrict__ w2b,
    const int* __restrict__ counts, const int* __restrict__ offsets,
    float* __restrict__ y0, float* __restrict__ y1,
    float* __restrict__ y2, float* __restrict__ y3)
{
    const int bid = blockIdx.x;           // 0..4095
    const int k = bid & 7;                // target XCD
    const int s = bid >> 3;               // 0..511
    const int ntile = s & 7;              // 0..7 (D/256)
    const int q = s >> 3;                 // 0..63
    const int ks = q & 3;                 // K-split index 0..3
    const int p = q >> 2;                 // 0..15
    const int e = p >> 1;
    const int mtile = ((k - e) & 7) + (p & 1) * 8;

    const int ne = counts[e];
    if (mtile * 256 >= ne) return;
    const int off = offsets[e];
    const int tid = threadIdx.x;
    const int lane = tid & 63;
    const int wid = tid >> 6;
    const int waveM = wid >> 2, waveN = wid & 3;   // 2M x 4N wave grid

    __shared__ alignas(16) bf16 As[2][256 * 64];   // 64KB
    __shared__ alignas(16) bf16 Bs[2][256 * 64];   // 64KB

    const int gg = tid & 7;
    const int r0 = tid >> 3;
    const int sgg = gg ^ (r0 & 7);

    const char* asrc[4];
#pragma unroll
    for (int i = 0; i < 4; ++i) {
        const int rg = mtile * 256 + i * 64 + r0;
        const int rc = rg < ne ? rg : ne - 1;
        asrc[i] = (const char*)(hbuf + (size_t)(off + rc) * NH) + sgg * 16;
    }
    const char* bsrc = (const char*)(w2b + (size_t)e * ND * NH
                       + (size_t)(ntile * 256 + r0) * NH) + sgg * 16;
    const size_t bstep = (size_t)64 * NH * 2;

    f32x4 acc[8][4];
#pragma unroll
    for (int i = 0; i < 8; ++i)
#pragma unroll
        for (int j = 0; j < 4; ++j) acc[i][j] = (f32x4)0.f;

    const int hi = lane >> 4, lo = lane & 15;

    auto stage = [&](int b, int kt) {   // 8 global_load_lds_dwordx4 per thread
        const int kb = kt * 128;
        char* ad = (char*)&As[b][0] + tid * 16;
        char* bd = (char*)&Bs[b][0] + tid * 16;
#pragma unroll
        for (int i = 0; i < 4; ++i) gload16(asrc[i] + kb, ad + i * 8192);
#pragma unroll
        for (int i = 0; i < 4; ++i) gload16(bsrc + i * bstep + kb, bd + i * 8192);
    };

    const int kt0 = ks * 16;
    const int kt1 = kt0 + 16;             // NH/64 = 64 total, 16 per split
    stage(0, kt0);
    int cur = 0;
    for (int kt = kt0; kt < kt1; ++kt) {
        if (kt + 1 < kt1) {
            stage(cur ^ 1, kt + 1);
            asm volatile("s_waitcnt vmcnt(8)" ::: "memory");
        } else {
            asm volatile("s_waitcnt vmcnt(0)" ::: "memory");
        }
        __builtin_amdgcn_s_barrier();
        __builtin_amdgcn_sched_barrier(0);
        const char* Ab = (const char*)&As[cur][0];
        const char* Bb = (const char*)&Bs[cur][0];
#pragma unroll
        for (int kk = 0; kk < 2; ++kk) {
            bf16x8 a[8], b[4];
            const int g = ((kk * 4 + hi) ^ (lo & 7)) * 16;
#pragma unroll
            for (int i = 0; i < 8; ++i)
                a[i] = *(const bf16x8*)(Ab + (waveM * 128 + i * 16 + lo) * 128 + g);
#pragma unroll
            for (int i = 0; i < 4; ++i)
                b[i] = *(const bf16x8*)(Bb + (waveN * 64 + i * 16 + lo) * 128 + g);
#pragma unroll
            for (int mi = 0; mi < 8; ++mi)
#pragma unroll
                for (int ni = 0; ni < 4; ++ni)
                    acc[mi][ni] = __builtin_amdgcn_mfma_f32_16x16x32_bf16(a[mi], b[ni], acc[mi][ni], 0, 0, 0);
        }
        __builtin_amdgcn_sched_barrier(0);
        asm volatile("" ::: "memory");
        __builtin_amdgcn_s_barrier();
        cur ^= 1;
    }

    // epilogue: raw partial rows into ybuf[ks]
    float* ybuf = (ks == 0) ? y0 : (ks == 1) ? y1 : (ks == 2) ? y2 : y3;
#pragma unroll
    for (int mi = 0; mi < 8; ++mi) {
#pragma unroll
        for (int r = 0; r < 4; ++r) {
            const int rowg = mtile * 256 + waveM * 128 + mi * 16 + hi * 4 + r;
            if (rowg < ne) {
                const int pp = off + rowg;
                float* yrow = ybuf + (size_t)pp * ND + ntile * 256 + waveN * 64 + lo;
#pragma unroll
                for (int ni = 0; ni < 4; ++ni)
                    yrow[ni * 16] = acc[mi][ni][r];
            }
        }
    }
}

// ========== FALLBACK PATH (round-1, fp32 loads + convert) ==========
__global__ __launch_bounds__(256) void gemm1_kernel(
    const float* __restrict__ x, const float* __restrict__ w1,
    const float* __restrict__ w3, const int* __restrict__ counts,
    const int* __restrict__ offsets, const int* __restrict__ ptok,
    bf16* __restrict__ hbuf)
{
    const int e = blockIdx.z;
    const int ne = counts[e];
    const int mtile = blockIdx.y;
    if (mtile * 128 >= ne) return;
    const int ntile = blockIdx.x;
    const int off = offsets[e];
    const int tid = threadIdx.x;
    const int lane = tid & 63;
    const int wid = tid >> 6;
    const int waveM = wid >> 1, waveN = wid & 1;

    __shared__ alignas(16) bf16 As[128 * 64];
    __shared__ alignas(16) bf16 B1s[128 * 64];
    __shared__ alignas(16) bf16 B3s[128 * 64];

    const int srow = tid >> 4;
    const int f4c = tid & 15;
    const int sg = (f4c >> 1) ^ (srow & 7);
    const int sub8 = (f4c & 1) * 8;

    const float* aptr[8];
#pragma unroll
    for (int p = 0; p < 8; ++p) {
        const int rg = mtile * 128 + p * 16 + srow;
        const int rc = rg < ne ? rg : ne - 1;
        const int tok = ptok[off + rc];
        aptr[p] = x + (size_t)tok * ND + f4c * 4;
    }
    const float* b1ptr = w1 + (size_t)e * NH * ND + (size_t)(ntile * 128 + srow) * ND + f4c * 4;
    const float* b3ptr = w3 + (size_t)e * NH * ND + (size_t)(ntile * 128 + srow) * ND + f4c * 4;

    f32x4 accG[4][4], accU[4][4];
#pragma unroll
    for (int i = 0; i < 4; ++i)
#pragma unroll
        for (int j = 0; j < 4; ++j) { accG[i][j] = (f32x4)0.f; accU[i][j] = (f32x4)0.f; }

    const int hi = lane >> 4, lo = lane & 15;

    for (int kt = 0; kt < ND / 64; ++kt) {
        __syncthreads();
#pragma unroll
        for (int p = 0; p < 8; ++p) {
            const float4 av = *(const float4*)(aptr[p] + kt * 64);
            const float4 bv1 = *(const float4*)(b1ptr + (size_t)p * 16 * ND + kt * 64);
            const float4 bv3 = *(const float4*)(b3ptr + (size_t)p * 16 * ND + kt * 64);
            const int dstb = (p * 16 + srow) * 128 + sg * 16 + sub8;
            bf16x4 a = {(bf16)av.x, (bf16)av.y, (bf16)av.z, (bf16)av.w};
            bf16x4 b1v = {(bf16)bv1.x, (bf16)bv1.y, (bf16)bv1.z, (bf16)bv1.w};
            bf16x4 b3v = {(bf16)bv3.x, (bf16)bv3.y, (bf16)bv3.z, (bf16)bv3.w};
            *(bf16x4*)((char*)As + dstb) = a;
            *(bf16x4*)((char*)B1s + dstb) = b1v;
            *(bf16x4*)((char*)B3s + dstb) = b3v;
        }
        __syncthreads();
#pragma unroll
        for (int kk = 0; kk < 2; ++kk) {
            bf16x8 a[4], bg[4], bu[4];
            const int g = ((kk * 4 + hi) ^ (lo & 7)) * 16;
#pragma unroll
            for (int i = 0; i < 4; ++i) {
                const int rowA = waveM * 64 + i * 16 + lo;
                a[i] = *(const bf16x8*)((const char*)As + rowA * 128 + g);
                const int rowB = waveN * 64 + i * 16 + lo;
                bg[i] = *(const bf16x8*)((const char*)B1s + rowB * 128 + g);
                bu[i] = *(const bf16x8*)((const char*)B3s + rowB * 128 + g);
            }
#pragma unroll
            for (int mi = 0; mi < 4; ++mi)
#pragma unroll
                for (int ni = 0; ni < 4; ++ni) {
                    accG[mi][ni] = __builtin_amdgcn_mfma_f32_16x16x32_bf16(a[mi], bg[ni], accG[mi][ni], 0, 0, 0);
                    accU[mi][ni] = __builtin_amdgcn_mfma_f32_16x16x32_bf16(a[mi], bu[ni], accU[mi][ni], 0, 0, 0);
                }
        }
    }

#pragma unroll
    for (int mi = 0; mi < 4; ++mi) {
#pragma unroll
        for (int r = 0; r < 4; ++r) {
            const int rowg = mtile * 128 + waveM * 64 + mi * 16 + hi * 4 + r;
            if (rowg < ne) {
                const size_t p = (size_t)(off + rowg);
                bf16* hrow = hbuf + p * NH + ntile * 128 + waveN * 64 + lo;
#pragma unroll
                for (int ni = 0; ni < 4; ++ni) {
                    const float gv = accG[mi][ni][r];
                    const float uv = accU[mi][ni][r];
                    const float h = (gv / (1.f + __expf(-gv))) * uv;
                    hrow[ni * 16] = (bf16)h;
                }
            }
        }
    }
}

__global__ __launch_bounds__(256) void gemm2_kernel(
    const bf16* __restrict__ hbuf, const float* __restrict__ w2,
    const int* __restrict__ counts, const int* __restrict__ offsets,
    const int* __restrict__ ptok, const float* __restrict__ pcw,
    float* __restrict__ out)
{
    const int e = blockIdx.z;
    const int ne = counts[e];
    const int mtile = blockIdx.y;
    if (mtile * 128 >= ne) return;
    const int ntile = blockIdx.x;
    const int off = offsets[e];
    const int tid = threadIdx.x;
    const int lane = tid & 63;
    const int wid = tid >> 6;
    const int waveM = wid >> 1, waveN = wid & 1;

    __shared__ alignas(16) bf16 As[128 * 64];
    __shared__ alignas(16) bf16 Bs[128 * 64];

    const int arow = tid >> 3;
    const int ag = tid & 7;
    const int aswz = ag ^ (arow & 7);
    const bf16* aptr[4];
#pragma unroll
    for (int p = 0; p < 4; ++p) {
        const int rg = mtile * 128 + p * 32 + arow;
        const int rc = rg < ne ? rg : ne - 1;
        aptr[p] = hbuf + (size_t)(off + rc) * NH + ag * 8;
    }
    const int srow = tid >> 4;
    const int f4c = tid & 15;
    const int bsg = (f4c >> 1) ^ (srow & 7);
    const int bsub8 = (f4c & 1) * 8;
    const float* bptr = w2 + (size_t)e * ND * NH + (size_t)(ntile * 128 + srow) * NH + f4c * 4;

    f32x4 acc[4][4];
#pragma unroll
    for (int i = 0; i < 4; ++i)
#pragma unroll
        for (int j = 0; j < 4; ++j) acc[i][j] = (f32x4)0.f;

    const int hi = lane >> 4, lo = lane & 15;

    for (int kt = 0; kt < NH / 64; ++kt) {
        __syncthreads();
#pragma unroll
        for (int p = 0; p < 4; ++p) {
            const bf16x8 av = *(const bf16x8*)(aptr[p] + kt * 64);
            *(bf16x8*)((char*)As + (p * 32 + arow) * 128 + aswz * 16) = av;
        }
#pragma unroll
        for (int p = 0; p < 8; ++p) {
            const float4 bv = *(const float4*)(bptr + (size_t)p * 16 * NH + kt * 64);
            bf16x4 b = {(bf16)bv.x, (bf16)bv.y, (bf16)bv.z, (bf16)bv.w};
            *(bf16x4*)((char*)Bs + (p * 16 + srow) * 128 + bsg * 16 + bsub8) = b;
        }
        __syncthreads();
#pragma unroll
        for (int kk = 0; kk < 2; ++kk) {
            bf16x8 a[4], b[4];
            const int g = ((kk * 4 + hi) ^ (lo & 7)) * 16;
#pragma unroll
            for (int i = 0; i < 4; ++i) {
                const int rowA = waveM * 64 + i * 16 + lo;
                a[i] = *(const bf16x8*)((const char*)As + rowA * 128 + g);
                const int rowB = waveN * 64 + i * 16 + lo;
                b[i] = *(const bf16x8*)((const char*)Bs + rowB * 128 + g);
            }
#pragma unroll
            for (int mi = 0; mi < 4; ++mi)
#pragma unroll
                for (int ni = 0; ni < 4; ++ni)
                    acc[mi][ni] = __builtin_amdgcn_mfma_f32_16x16x32_bf16(a[mi], b[ni], acc[mi][ni], 0, 0, 0);
        }
    }

#pragma unroll
    for (int mi = 0; mi < 4; ++mi) {
#pragma unroll
        for (int r = 0; r < 4; ++r) {
            const int rowg = mtile * 128 + waveM * 64 + mi * 16 + hi * 4 + r;
            if (rowg < ne) {
                const int p = off + rowg;
                const int tok = ptok[p];
                const float c = pcw[p];
                float* orow = out + (size_t)tok * ND + ntile * 128 + waveN * 64 + lo;
#pragma unroll
                for (int ni = 0; ni < 4; ++ni)
                    atomicAdd(orow + ni * 16, c * acc[mi][ni][r]);
            }
        }
    }
}

extern "C" void kernel_launch(void* const* d_in, const int* in_sizes, int n_in,
                              void* d_out, int out_size, void* d_ws, size_t ws_size,
                              hipStream_t stream)
{
    const float* x  = (const float*)d_in[0];
    const float* rw = (const float*)d_in[1];
    const float* w1 = (const float*)d_in[2];
    const float* w3 = (const float*)d_in[3];
    const float* w2 = (const float*)d_in[4];
    float* out = (float*)d_out;
    char* ws = (char*)d_ws;

    int*   counts  = (int*)(ws + 0);
    int*   cursor  = (int*)(ws + 32);
    int*   offsets = (int*)(ws + 64);
    int*   sel     = (int*)(ws + 128);
    float* cw      = (float*)(ws + 32896);
    int*   ptok    = (int*)(ws + 65664);
    float* pcw     = (float*)(ws + 98432);
    int*   tpair   = (int*)(ws + 131200);
    bf16*  hbuf    = (bf16*)(ws + 262144);

    const size_t MB = 1024 * 1024;
    bf16*  xb  = (bf16*)(ws + 68 * MB);
    float* y0  = (float*)(ws + 96 * MB);      // overlay w1b/w3b (dead after gemm1)
    float* y1  = (float*)(ws + 160 * MB);
    float* y2  = (float*)(ws + 224 * MB);
    float* y3  = (float*)(ws + 288 * MB);
    bf16*  w1b = (bf16*)(ws + 96 * MB);
    bf16*  w3b = (bf16*)(ws + 224 * MB);
    bf16*  w2b = (bf16*)(ws + 352 * MB);
    const bool fast = ws_size >= 480 * MB;

    hipMemsetAsync(ws, 0, 128, stream);

    if (fast) {
        router_kernel<<<NT, 64, 0, stream>>>(x, rw, counts, sel, cw, xb);
        prefix_kernel<<<1, 1, 0, stream>>>(counts, cursor, offsets);
        scatter_kernel<<<NT / 256, 256, 0, stream>>>(sel, cw, offsets, cursor, ptok, pcw, tpair);
        cvt13_kernel<<<4096, 256, 0, stream>>>(w1, w1b, w3, w3b);
        gemm1b_kernel<<<5120, 512, 0, stream>>>(xb, w1b, w3b, counts, offsets, ptok, hbuf, w2, w2b);
        gemm2b_kernel<<<4096, 512, 0, stream>>>(hbuf, w2b, counts, offsets, y0, y1, y2, y3);
        combine_kernel<<<2048, 256, 0, stream>>>(y0, y1, y2, y3, tpair, cw, out);
    } else {
        router_kernel<<<NT, 64, 0, stream>>>(x, rw, counts, sel, cw, nullptr);
        prefix_kernel<<<1, 1, 0, stream>>>(counts, cursor, offsets);
        scatter_kernel<<<NT / 256, 256, 0, stream>>>(sel, cw, offsets, cursor, ptok, pcw, tpair);
        hipMemsetAsync(d_out, 0, (size_t)out_size * sizeof(float), stream);
        gemm1_kernel<<<dim3(NH / 128, 32, NE), 256, 0, stream>>>(x, w1, w3, counts, offsets, ptok, hbuf);
        gemm2_kernel<<<dim3(ND / 128, 32, NE), 256, 0, stream>>>(hbuf, w2, counts, offsets, ptok, pcw, out);
    }
}

// Round 15
// 977.844 us; speedup vs baseline: 1.0270x; 1.0270x over previous
//
#include <hip/hip_runtime.h>

// MoE feed-forward, top-2 of 8 experts. T=4096, D=2048, H=4096, E=8, fp32 io.
// Round 15: REVERT to round-13 exact (best measured, 978us). Round-14's
// split-K x4 regressed (1004); split-K x2 is the optimum on that axis.
//   - router (emits bf16 x), prefix, scatter
//   - cvt13: w1/w3 fp32->bf16 (BW floor ~140us)
//   - gemm1b: 256x128, counted-vmcnt depth-2, nsub-innermost XCD decode,
//     fused w2->bf16 role blocks [434us, MfmaUtil 29.5, 634 TF ~ 97% of
//     2-phase grouped-GEMM ceiling]
//   - gemm2b: 256x256, same schedule, split-K x2, (mtile+e)&7 XCD decode
//   - combine: y0+y1 weighted sum
//
// ws layout:
//   [0,32) counts  [32,64) cursor  [64,96) offsets
//   [128,+32K) sel[T][2]   [32896,..) cw[T][2]
//   [65664,..) pair_token[8192]  [98432,..) pair_cw[8192]
//   [131200,..) tpair[T][2]
//   [256K, +64MB)  hbuf bf16 [8192][H]
//   [68MB, +16MB)  xb  bf16 [T][D]
//   [96MB, +64MB)  ybuf0 f32 [8192][D]  (overlays w1b, dead after gemm1)
//   [160MB,+64MB)  ybuf1 f32 [8192][D]
//   [96MB, +128MB) w1b bf16 [E][H][D]
//   [224MB,+128MB) w3b bf16 [E][H][D]
//   [352MB,+128MB) w2b bf16 [E][D][H]
// fast path needs 480MB; falls back to round-1 fp32-load path otherwise.

#define NT 4096
#define ND 2048
#define NH 4096
#define NE 8

typedef __bf16 bf16;
typedef __attribute__((ext_vector_type(4))) __bf16 bf16x4;
typedef __attribute__((ext_vector_type(8))) __bf16 bf16x8;
typedef __attribute__((ext_vector_type(4))) float f32x4;

__device__ __forceinline__ void gload16(const void* g, void* l) {
    __builtin_amdgcn_global_load_lds(
        (const __attribute__((address_space(1))) void*)g,
        (__attribute__((address_space(3))) void*)l, 16, 0, 0);
}

// ---------------- router: logits -> top2 -> renorm; emits bf16 x ----------------
__global__ __launch_bounds__(64) void router_kernel(
    const float* __restrict__ x, const float* __restrict__ rweights,
    int* __restrict__ counts, int* __restrict__ sel, float* __restrict__ cw,
    bf16* __restrict__ xb)
{
    const int t = blockIdx.x;
    const int lane = threadIdx.x;
    float acc[NE];
#pragma unroll
    for (int e = 0; e < NE; ++e) acc[e] = 0.f;
    const float* xr = x + (size_t)t * ND;
#pragma unroll
    for (int i = 0; i < ND / 256; ++i) {          // 8 iters of float4
        const int d4 = i * 64 + lane;
        const float4 xv = ((const float4*)xr)[d4];
        if (xb != nullptr) {
            bf16x4 v = {(bf16)xv.x, (bf16)xv.y, (bf16)xv.z, (bf16)xv.w};
            *(bf16x4*)(xb + (size_t)t * ND + d4 * 4) = v;
        }
#pragma unroll
        for (int e = 0; e < NE; ++e) {
            const float4 wv = ((const float4*)(rweights + e * ND))[d4];
            acc[e] += xv.x * wv.x + xv.y * wv.y + xv.z * wv.z + xv.w * wv.w;
        }
    }
#pragma unroll
    for (int e = 0; e < NE; ++e) {
#pragma unroll
        for (int off = 32; off > 0; off >>= 1)
            acc[e] += __shfl_xor(acc[e], off);
    }
    if (lane == 0) {
        int e0 = 0;
#pragma unroll
        for (int e = 1; e < NE; ++e) if (acc[e] > acc[e0]) e0 = e;
        int e1 = (e0 == 0) ? 1 : 0;
#pragma unroll
        for (int e = 0; e < NE; ++e) if (e != e0 && acc[e] > acc[e1]) e1 = e;
        const float w0 = 1.f / (1.f + expf(acc[e1] - acc[e0]));
        sel[t * 2 + 0] = e0; sel[t * 2 + 1] = e1;
        cw[t * 2 + 0] = w0;  cw[t * 2 + 1] = 1.f - w0;
        atomicAdd(&counts[e0], 1);
        atomicAdd(&counts[e1], 1);
    }
}

__global__ void prefix_kernel(int* __restrict__ counts, int* __restrict__ cursor,
                              int* __restrict__ offsets)
{
    int s = 0;
    for (int e = 0; e < NE; ++e) { offsets[e] = s; s += counts[e]; cursor[e] = 0; }
}

__global__ __launch_bounds__(256) void scatter_kernel(
    const int* __restrict__ sel, const float* __restrict__ cw,
    const int* __restrict__ offsets, int* __restrict__ cursor,
    int* __restrict__ ptok, float* __restrict__ pcw, int* __restrict__ tpair)
{
    const int t = blockIdx.x * 256 + threadIdx.x;
    if (t >= NT) return;
#pragma unroll
    for (int k = 0; k < 2; ++k) {
        const int e = sel[t * 2 + k];
        const int pos = atomicAdd(&cursor[e], 1);
        const int idx = offsets[e] + pos;
        ptok[idx] = t;
        pcw[idx] = cw[t * 2 + k];
        tpair[t * 2 + k] = idx;
    }
}

// ---------------- fp32 -> bf16 conversion for w1,w3 only ----------------
__global__ __launch_bounds__(256) void cvt13_kernel(
    const float* __restrict__ w1, bf16* __restrict__ w1b,
    const float* __restrict__ w3, bf16* __restrict__ w3b)
{
    const int nw = NE * NH * ND / 8;
    const int total = 2 * nw;
    for (int i = blockIdx.x * 256 + threadIdx.x; i < total; i += gridDim.x * 256) {
        const float* s; bf16* d; int j;
        if (i < nw) { s = w1; d = w1b; j = i; }
        else        { s = w3; d = w3b; j = i - nw; }
        const float4 a = ((const float4*)s)[2 * (size_t)j];
        const float4 b = ((const float4*)s)[2 * (size_t)j + 1];
        bf16x8 v = {(bf16)a.x, (bf16)a.y, (bf16)a.z, (bf16)a.w,
                    (bf16)b.x, (bf16)b.y, (bf16)b.z, (bf16)b.w};
        *(bf16x8*)(d + 8 * (size_t)j) = v;
    }
}

// ---------------- combine: out[t] = sum_k cw_k * (y0[p_k] + y1[p_k]) ----------------
__global__ __launch_bounds__(256) void combine_kernel(
    const float* __restrict__ y0buf, const float* __restrict__ y1buf,
    const int* __restrict__ tpair, const float* __restrict__ cw,
    float* __restrict__ out)
{
    const int total = NT * ND / 4;
    for (int i = blockIdx.x * 256 + threadIdx.x; i < total; i += gridDim.x * 256) {
        const int t = i >> 9;            // ND/4 = 512 float4 per token
        const int c = i & 511;
        const int p0 = tpair[t * 2 + 0], p1 = tpair[t * 2 + 1];
        const float w0 = cw[t * 2 + 0], w1 = cw[t * 2 + 1];
        const float4 a0 = ((const float4*)(y0buf + (size_t)p0 * ND))[c];
        const float4 b0 = ((const float4*)(y1buf + (size_t)p0 * ND))[c];
        const float4 a1 = ((const float4*)(y0buf + (size_t)p1 * ND))[c];
        const float4 b1 = ((const float4*)(y1buf + (size_t)p1 * ND))[c];
        float4 o;
        o.x = w0 * (a0.x + b0.x) + w1 * (a1.x + b1.x);
        o.y = w0 * (a0.y + b0.y) + w1 * (a1.y + b1.y);
        o.z = w0 * (a0.z + b0.z) + w1 * (a1.z + b1.z);
        o.w = w0 * (a0.w + b0.w) + w1 * (a1.w + b1.w);
        ((float4*)(out + (size_t)t * ND))[c] = o;
    }
}

// ========== FAST PATH gemm1b: round-8 exact (counted-vmcnt depth-2 + w2 cvt) ==========
// LDS content(row, granule gg) = global[row][gg ^ (row&7)]; reads use
// granule (k_granule ^ (row&7)) — swizzle pair verified rounds 1-14.

__global__ __launch_bounds__(512, 2) void gemm1b_kernel(
    const bf16* __restrict__ xb, const bf16* __restrict__ w1b,
    const bf16* __restrict__ w3b, const int* __restrict__ counts,
    const int* __restrict__ offsets, const int* __restrict__ ptok,
    bf16* __restrict__ hbuf,
    const float* __restrict__ w2, bf16* __restrict__ w2b)
{
    const int bid = blockIdx.x;
    const int tid = threadIdx.x;

    if (bid >= 4096) {
        // w2 conversion role: 1024 blocks x 512 threads, 16 float8 each
        const int idx = (bid - 4096) * 512 + tid;
#pragma unroll
        for (int j = 0; j < 16; ++j) {
            const size_t i = (size_t)idx + (size_t)j * (1024 * 512);
            const float4 a = ((const float4*)w2)[2 * i];
            const float4 b = ((const float4*)w2)[2 * i + 1];
            bf16x8 v = {(bf16)a.x, (bf16)a.y, (bf16)a.z, (bf16)a.w,
                        (bf16)b.x, (bf16)b.y, (bf16)b.z, (bf16)b.w};
            *(bf16x8*)(w2b + 8 * i) = v;
        }
        return;
    }

    // decode: xcd = bid&7 gets ntile group [4*xcd, 4*xcd+4) for ALL (e,mtile)
    const int xcd = bid & 7;
    const int s = bid >> 3;                  // 0..511
    const int ntile = xcd * 4 + (s & 3);     // 0..31
    const int em = s >> 2;                   // 0..127
    const int mtile = em & 15;
    const int e = em >> 4;

    const int ne = counts[e];
    if (mtile * 256 >= ne) return;
    const int off = offsets[e];
    const int lane = tid & 63;
    const int wid = tid >> 6;
    const int waveM = wid >> 1, waveN = wid & 1;   // 4M x 2N wave grid

    __shared__ alignas(16) bf16 As[2][256 * 64];   // 64KB
    __shared__ alignas(16) bf16 B1s[2][128 * 64];  // 32KB
    __shared__ alignas(16) bf16 B3s[2][128 * 64];  // 32KB

    const int gg = tid & 7;
    const int r0 = tid >> 3;                 // 0..63
    const int sgg = gg ^ (r0 & 7);           // pre-swizzled SOURCE granule

    const char* asrc[4];
#pragma unroll
    for (int i = 0; i < 4; ++i) {
        const int rg = mtile * 256 + i * 64 + r0;
        const int rc = rg < ne ? rg : ne - 1;
        const int tok = ptok[off + rc];
        asrc[i] = (const char*)(xb + (size_t)tok * ND) + sgg * 16;
    }
    const char* b1src = (const char*)(w1b + (size_t)e * NH * ND
                        + (size_t)(ntile * 128 + r0) * ND) + sgg * 16;
    const char* b3src = (const char*)(w3b + (size_t)e * NH * ND
                        + (size_t)(ntile * 128 + r0) * ND) + sgg * 16;
    const size_t bstep = (size_t)64 * ND * 2;

    f32x4 accG[4][4], accU[4][4];
#pragma unroll
    for (int i = 0; i < 4; ++i)
#pragma unroll
        for (int j = 0; j < 4; ++j) { accG[i][j] = (f32x4)0.f; accU[i][j] = (f32x4)0.f; }

    const int hi = lane >> 4, lo = lane & 15;

    auto stage = [&](int b, int kt) {   // 8 global_load_lds_dwordx4 per thread
        const int kb = kt * 128;
        char* ad  = (char*)&As[b][0]  + tid * 16;
        char* b1d = (char*)&B1s[b][0] + tid * 16;
        char* b3d = (char*)&B3s[b][0] + tid * 16;
#pragma unroll
        for (int i = 0; i < 4; ++i) gload16(asrc[i] + kb, ad + i * 8192);
#pragma unroll
        for (int i = 0; i < 2; ++i) gload16(b1src + i * bstep + kb, b1d + i * 8192);
#pragma unroll
        for (int i = 0; i < 2; ++i) gload16(b3src + i * bstep + kb, b3d + i * 8192);
    };

    stage(0, 0);
    int cur = 0;
    const int NK = ND / 64;
    for (int kt = 0; kt < NK; ++kt) {
        if (kt + 1 < NK) {
            stage(cur ^ 1, kt + 1);   // prefetch next K-tile (stays in flight)
            asm volatile("s_waitcnt vmcnt(8)" ::: "memory");  // tile kt landed
        } else {
            asm volatile("s_waitcnt vmcnt(0)" ::: "memory");
        }
        __builtin_amdgcn_s_barrier();
        __builtin_amdgcn_sched_barrier(0);
        const char* Ab  = (const char*)&As[cur][0];
        const char* B1b = (const char*)&B1s[cur][0];
        const char* B3b = (const char*)&B3s[cur][0];
#pragma unroll
        for (int kk = 0; kk < 2; ++kk) {
            bf16x8 a[4], bg[4], bu[4];
            const int g = ((kk * 4 + hi) ^ (lo & 7)) * 16;
#pragma unroll
            for (int i = 0; i < 4; ++i) {
                a[i]  = *(const bf16x8*)(Ab  + (waveM * 64 + i * 16 + lo) * 128 + g);
                bg[i] = *(const bf16x8*)(B1b + (waveN * 64 + i * 16 + lo) * 128 + g);
                bu[i] = *(const bf16x8*)(B3b + (waveN * 64 + i * 16 + lo) * 128 + g);
            }
#pragma unroll
            for (int mi = 0; mi < 4; ++mi)
#pragma unroll
                for (int ni = 0; ni < 4; ++ni) {
                    accG[mi][ni] = __builtin_amdgcn_mfma_f32_16x16x32_bf16(a[mi], bg[ni], accG[mi][ni], 0, 0, 0);
                    accU[mi][ni] = __builtin_amdgcn_mfma_f32_16x16x32_bf16(a[mi], bu[ni], accU[mi][ni], 0, 0, 0);
                }
        }
        __builtin_amdgcn_sched_barrier(0);
        asm volatile("" ::: "memory");
        __builtin_amdgcn_s_barrier();     // all waves done reading buf[cur]
        cur ^= 1;
    }

    // epilogue: h = silu(gate)*up -> bf16 hbuf[pair][H]
#pragma unroll
    for (int mi = 0; mi < 4; ++mi) {
#pragma unroll
        for (int r = 0; r < 4; ++r) {
            const int rowg = mtile * 256 + waveM * 64 + mi * 16 + hi * 4 + r;
            if (rowg < ne) {
                const size_t p = (size_t)(off + rowg);
                bf16* hrow = hbuf + p * NH + ntile * 128 + waveN * 64 + lo;
#pragma unroll
                for (int ni = 0; ni < 4; ++ni) {
                    const float gv = accG[mi][ni][r];
                    const float uv = accU[mi][ni][r];
                    const float h = (gv / (1.f + __expf(-gv))) * uv;
                    hrow[ni * 16] = (bf16)h;
                }
            }
        }
    }
}

// gemm2b: 256x256 tile, 8 waves 2Mx4N, round-8 schedule, SPLIT-K x2:
// each block computes K-half ks (2048 wide, NK=32) and writes its partial
// to ybuf[ks]. 2048 blocks declared, 512 active -> 2 slots/CU.
// XCD decode: xcd = (mtile + e) & 7 keeps A-panel sharers on one XCD.
__global__ __launch_bounds__(512, 2) void gemm2b_kernel(
    const bf16* __restrict__ hbuf, const bf16* __restrict__ w2b,
    const int* __restrict__ counts, const int* __restrict__ offsets,
    float* __restrict__ y0buf, float* __restrict__ y1buf)
{
    const int bid = blockIdx.x;           // 0..2047
    const int k = bid & 7;                // target XCD
    const int s = bid >> 3;               // 0..255
    const int ntile = s & 7;              // 0..7 (D/256)
    const int q = s >> 3;                 // 0..31
    const int ks = q & 1;                 // K-split index
    const int p = q >> 1;                 // 0..15
    const int e = p >> 1;
    const int mtile = ((k - e) & 7) + (p & 1) * 8;

    const int ne = counts[e];
    if (mtile * 256 >= ne) return;
    const int off = offsets[e];
    const int tid = threadIdx.x;
    const int lane = tid & 63;
    const int wid = tid >> 6;
    const int waveM = wid >> 2, waveN = wid & 3;   // 2M x 4N wave grid

    __shared__ alignas(16) bf16 As[2][256 * 64];   // 64KB
    __shared__ alignas(16) bf16 Bs[2][256 * 64];   // 64KB

    const int gg = tid & 7;
    const int r0 = tid >> 3;
    const int sgg = gg ^ (r0 & 7);

    const char* asrc[4];
#pragma unroll
    for (int i = 0; i < 4; ++i) {
        const int rg = mtile * 256 + i * 64 + r0;
        const int rc = rg < ne ? rg : ne - 1;
        asrc[i] = (const char*)(hbuf + (size_t)(off + rc) * NH) + sgg * 16;
    }
    const char* bsrc = (const char*)(w2b + (size_t)e * ND * NH
                       + (size_t)(ntile * 256 + r0) * NH) + sgg * 16;
    const size_t bstep = (size_t)64 * NH * 2;

    f32x4 acc[8][4];
#pragma unroll
    for (int i = 0; i < 8; ++i)
#pragma unroll
        for (int j = 0; j < 4; ++j) acc[i][j] = (f32x4)0.f;

    const int hi = lane >> 4, lo = lane & 15;

    auto stage = [&](int b, int kt) {   // 8 global_load_lds_dwordx4 per thread
        const int kb = kt * 128;
        char* ad = (char*)&As[b][0] + tid * 16;
        char* bd = (char*)&Bs[b][0] + tid * 16;
#pragma unroll
        for (int i = 0; i < 4; ++i) gload16(asrc[i] + kb, ad + i * 8192);
#pragma unroll
        for (int i = 0; i < 4; ++i) gload16(bsrc + i * bstep + kb, bd + i * 8192);
    };

    const int kt0 = ks * 32;
    const int kt1 = kt0 + 32;             // NH/64 = 64 total, 32 per split
    stage(0, kt0);
    int cur = 0;
    for (int kt = kt0; kt < kt1; ++kt) {
        if (kt + 1 < kt1) {
            stage(cur ^ 1, kt + 1);
            asm volatile("s_waitcnt vmcnt(8)" ::: "memory");
        } else {
            asm volatile("s_waitcnt vmcnt(0)" ::: "memory");
        }
        __builtin_amdgcn_s_barrier();
        __builtin_amdgcn_sched_barrier(0);
        const char* Ab = (const char*)&As[cur][0];
        const char* Bb = (const char*)&Bs[cur][0];
#pragma unroll
        for (int kk = 0; kk < 2; ++kk) {
            bf16x8 a[8], b[4];
            const int g = ((kk * 4 + hi) ^ (lo & 7)) * 16;
#pragma unroll
            for (int i = 0; i < 8; ++i)
                a[i] = *(const bf16x8*)(Ab + (waveM * 128 + i * 16 + lo) * 128 + g);
#pragma unroll
            for (int i = 0; i < 4; ++i)
                b[i] = *(const bf16x8*)(Bb + (waveN * 64 + i * 16 + lo) * 128 + g);
#pragma unroll
            for (int mi = 0; mi < 8; ++mi)
#pragma unroll
                for (int ni = 0; ni < 4; ++ni)
                    acc[mi][ni] = __builtin_amdgcn_mfma_f32_16x16x32_bf16(a[mi], b[ni], acc[mi][ni], 0, 0, 0);
        }
        __builtin_amdgcn_sched_barrier(0);
        asm volatile("" ::: "memory");
        __builtin_amdgcn_s_barrier();
        cur ^= 1;
    }

    // epilogue: raw partial rows into ybuf[ks]
    float* ybuf = ks ? y1buf : y0buf;
#pragma unroll
    for (int mi = 0; mi < 8; ++mi) {
#pragma unroll
        for (int r = 0; r < 4; ++r) {
            const int rowg = mtile * 256 + waveM * 128 + mi * 16 + hi * 4 + r;
            if (rowg < ne) {
                const int pp = off + rowg;
                float* yrow = ybuf + (size_t)pp * ND + ntile * 256 + waveN * 64 + lo;
#pragma unroll
                for (int ni = 0; ni < 4; ++ni)
                    yrow[ni * 16] = acc[mi][ni][r];
            }
        }
    }
}

// ========== FALLBACK PATH (round-1, fp32 loads + convert) ==========
__global__ __launch_bounds__(256) void gemm1_kernel(
    const float* __restrict__ x, const float* __restrict__ w1,
    const float* __restrict__ w3, const int* __restrict__ counts,
    const int* __restrict__ offsets, const int* __restrict__ ptok,
    bf16* __restrict__ hbuf)
{
    const int e = blockIdx.z;
    const int ne = counts[e];
    const int mtile = blockIdx.y;
    if (mtile * 128 >= ne) return;
    const int ntile = blockIdx.x;
    const int off = offsets[e];
    const int tid = threadIdx.x;
    const int lane = tid & 63;
    const int wid = tid >> 6;
    const int waveM = wid >> 1, waveN = wid & 1;

    __shared__ alignas(16) bf16 As[128 * 64];
    __shared__ alignas(16) bf16 B1s[128 * 64];
    __shared__ alignas(16) bf16 B3s[128 * 64];

    const int srow = tid >> 4;
    const int f4c = tid & 15;
    const int sg = (f4c >> 1) ^ (srow & 7);
    const int sub8 = (f4c & 1) * 8;

    const float* aptr[8];
#pragma unroll
    for (int p = 0; p < 8; ++p) {
        const int rg = mtile * 128 + p * 16 + srow;
        const int rc = rg < ne ? rg : ne - 1;
        const int tok = ptok[off + rc];
        aptr[p] = x + (size_t)tok * ND + f4c * 4;
    }
    const float* b1ptr = w1 + (size_t)e * NH * ND + (size_t)(ntile * 128 + srow) * ND + f4c * 4;
    const float* b3ptr = w3 + (size_t)e * NH * ND + (size_t)(ntile * 128 + srow) * ND + f4c * 4;

    f32x4 accG[4][4], accU[4][4];
#pragma unroll
    for (int i = 0; i < 4; ++i)
#pragma unroll
        for (int j = 0; j < 4; ++j) { accG[i][j] = (f32x4)0.f; accU[i][j] = (f32x4)0.f; }

    const int hi = lane >> 4, lo = lane & 15;

    for (int kt = 0; kt < ND / 64; ++kt) {
        __syncthreads();
#pragma unroll
        for (int p = 0; p < 8; ++p) {
            const float4 av = *(const float4*)(aptr[p] + kt * 64);
            const float4 bv1 = *(const float4*)(b1ptr + (size_t)p * 16 * ND + kt * 64);
            const float4 bv3 = *(const float4*)(b3ptr + (size_t)p * 16 * ND + kt * 64);
            const int dstb = (p * 16 + srow) * 128 + sg * 16 + sub8;
            bf16x4 a = {(bf16)av.x, (bf16)av.y, (bf16)av.z, (bf16)av.w};
            bf16x4 b1v = {(bf16)bv1.x, (bf16)bv1.y, (bf16)bv1.z, (bf16)bv1.w};
            bf16x4 b3v = {(bf16)bv3.x, (bf16)bv3.y, (bf16)bv3.z, (bf16)bv3.w};
            *(bf16x4*)((char*)As + dstb) = a;
            *(bf16x4*)((char*)B1s + dstb) = b1v;
            *(bf16x4*)((char*)B3s + dstb) = b3v;
        }
        __syncthreads();
#pragma unroll
        for (int kk = 0; kk < 2; ++kk) {
            bf16x8 a[4], bg[4], bu[4];
            const int g = ((kk * 4 + hi) ^ (lo & 7)) * 16;
#pragma unroll
            for (int i = 0; i < 4; ++i) {
                const int rowA = waveM * 64 + i * 16 + lo;
                a[i] = *(const bf16x8*)((const char*)As + rowA * 128 + g);
                const int rowB = waveN * 64 + i * 16 + lo;
                bg[i] = *(const bf16x8*)((const char*)B1s + rowB * 128 + g);
                bu[i] = *(const bf16x8*)((const char*)B3s + rowB * 128 + g);
            }
#pragma unroll
            for (int mi = 0; mi < 4; ++mi)
#pragma unroll
                for (int ni = 0; ni < 4; ++ni) {
                    accG[mi][ni] = __builtin_amdgcn_mfma_f32_16x16x32_bf16(a[mi], bg[ni], accG[mi][ni], 0, 0, 0);
                    accU[mi][ni] = __builtin_amdgcn_mfma_f32_16x16x32_bf16(a[mi], bu[ni], accU[mi][ni], 0, 0, 0);
                }
        }
    }

#pragma unroll
    for (int mi = 0; mi < 4; ++mi) {
#pragma unroll
        for (int r = 0; r < 4; ++r) {
            const int rowg = mtile * 128 + waveM * 64 + mi * 16 + hi * 4 + r;
            if (rowg < ne) {
                const size_t p = (size_t)(off + rowg);
                bf16* hrow = hbuf + p * NH + ntile * 128 + waveN * 64 + lo;
#pragma unroll
                for (int ni = 0; ni < 4; ++ni) {
                    const float gv = accG[mi][ni][r];
                    const float uv = accU[mi][ni][r];
                    const float h = (gv / (1.f + __expf(-gv))) * uv;
                    hrow[ni * 16] = (bf16)h;
                }
            }
        }
    }
}

__global__ __launch_bounds__(256) void gemm2_kernel(
    const bf16* __restrict__ hbuf, const float* __restrict__ w2,
    const int* __restrict__ counts, const int* __restrict__ offsets,
    const int* __restrict__ ptok, const float* __restrict__ pcw,
    float* __restrict__ out)
{
    const int e = blockIdx.z;
    const int ne = counts[e];
    const int mtile = blockIdx.y;
    if (mtile * 128 >= ne) return;
    const int ntile = blockIdx.x;
    const int off = offsets[e];
    const int tid = threadIdx.x;
    const int lane = tid & 63;
    const int wid = tid >> 6;
    const int waveM = wid >> 1, waveN = wid & 1;

    __shared__ alignas(16) bf16 As[128 * 64];
    __shared__ alignas(16) bf16 Bs[128 * 64];

    const int arow = tid >> 3;
    const int ag = tid & 7;
    const int aswz = ag ^ (arow & 7);
    const bf16* aptr[4];
#pragma unroll
    for (int p = 0; p < 4; ++p) {
        const int rg = mtile * 128 + p * 32 + arow;
        const int rc = rg < ne ? rg : ne - 1;
        aptr[p] = hbuf + (size_t)(off + rc) * NH + ag * 8;
    }
    const int srow = tid >> 4;
    const int f4c = tid & 15;
    const int bsg = (f4c >> 1) ^ (srow & 7);
    const int bsub8 = (f4c & 1) * 8;
    const float* bptr = w2 + (size_t)e * ND * NH + (size_t)(ntile * 128 + srow) * NH + f4c * 4;

    f32x4 acc[4][4];
#pragma unroll
    for (int i = 0; i < 4; ++i)
#pragma unroll
        for (int j = 0; j < 4; ++j) acc[i][j] = (f32x4)0.f;

    const int hi = lane >> 4, lo = lane & 15;

    for (int kt = 0; kt < NH / 64; ++kt) {
        __syncthreads();
#pragma unroll
        for (int p = 0; p < 4; ++p) {
            const bf16x8 av = *(const bf16x8*)(aptr[p] + kt * 64);
            *(bf16x8*)((char*)As + (p * 32 + arow) * 128 + aswz * 16) = av;
        }
#pragma unroll
        for (int p = 0; p < 8; ++p) {
            const float4 bv = *(const float4*)(bptr + (size_t)p * 16 * NH + kt * 64);
            bf16x4 b = {(bf16)bv.x, (bf16)bv.y, (bf16)bv.z, (bf16)bv.w};
            *(bf16x4*)((char*)Bs + (p * 16 + srow) * 128 + bsg * 16 + bsub8) = b;
        }
        __syncthreads();
#pragma unroll
        for (int kk = 0; kk < 2; ++kk) {
            bf16x8 a[4], b[4];
            const int g = ((kk * 4 + hi) ^ (lo & 7)) * 16;
#pragma unroll
            for (int i = 0; i < 4; ++i) {
                const int rowA = waveM * 64 + i * 16 + lo;
                a[i] = *(const bf16x8*)((const char*)As + rowA * 128 + g);
                const int rowB = waveN * 64 + i * 16 + lo;
                b[i] = *(const bf16x8*)((const char*)Bs + rowB * 128 + g);
            }
#pragma unroll
            for (int mi = 0; mi < 4; ++mi)
#pragma unroll
                for (int ni = 0; ni < 4; ++ni)
                    acc[mi][ni] = __builtin_amdgcn_mfma_f32_16x16x32_bf16(a[mi], b[ni], acc[mi][ni], 0, 0, 0);
        }
    }

#pragma unroll
    for (int mi = 0; mi < 4; ++mi) {
#pragma unroll
        for (int r = 0; r < 4; ++r) {
            const int rowg = mtile * 128 + waveM * 64 + mi * 16 + hi * 4 + r;
            if (rowg < ne) {
                const int p = off + rowg;
                const int tok = ptok[p];
                const float c = pcw[p];
                float* orow = out + (size_t)tok * ND + ntile * 128 + waveN * 64 + lo;
#pragma unroll
                for (int ni = 0; ni < 4; ++ni)
                    atomicAdd(orow + ni * 16, c * acc[mi][ni][r]);
            }
        }
    }
}

extern "C" void kernel_launch(void* const* d_in, const int* in_sizes, int n_in,
                              void* d_out, int out_size, void* d_ws, size_t ws_size,
                              hipStream_t stream)
{
    const float* x  = (const float*)d_in[0];
    const float* rw = (const float*)d_in[1];
    const float* w1 = (const float*)d_in[2];
    const float* w3 = (const float*)d_in[3];
    const float* w2 = (const float*)d_in[4];
    float* out = (float*)d_out;
    char* ws = (char*)d_ws;

    int*   counts  = (int*)(ws + 0);
    int*   cursor  = (int*)(ws + 32);
    int*   offsets = (int*)(ws + 64);
    int*   sel     = (int*)(ws + 128);
    float* cw      = (float*)(ws + 32896);
    int*   ptok    = (int*)(ws + 65664);
    float* pcw     = (float*)(ws + 98432);
    int*   tpair   = (int*)(ws + 131200);
    bf16*  hbuf    = (bf16*)(ws + 262144);

    const size_t MB = 1024 * 1024;
    bf16*  xb    = (bf16*)(ws + 68 * MB);
    float* y0buf = (float*)(ws + 96 * MB);    // overlays w1b (dead after gemm1)
    float* y1buf = (float*)(ws + 160 * MB);   // also dead w1b space
    bf16*  w1b   = (bf16*)(ws + 96 * MB);
    bf16*  w3b   = (bf16*)(ws + 224 * MB);
    bf16*  w2b   = (bf16*)(ws + 352 * MB);
    const bool fast = ws_size >= 480 * MB;

    hipMemsetAsync(ws, 0, 128, stream);

    if (fast) {
        router_kernel<<<NT, 64, 0, stream>>>(x, rw, counts, sel, cw, xb);
        prefix_kernel<<<1, 1, 0, stream>>>(counts, cursor, offsets);
        scatter_kernel<<<NT / 256, 256, 0, stream>>>(sel, cw, offsets, cursor, ptok, pcw, tpair);
        cvt13_kernel<<<4096, 256, 0, stream>>>(w1, w1b, w3, w3b);
        gemm1b_kernel<<<5120, 512, 0, stream>>>(xb, w1b, w3b, counts, offsets, ptok, hbuf, w2, w2b);
        gemm2b_kernel<<<2048, 512, 0, stream>>>(hbuf, w2b, counts, offsets, y0buf, y1buf);
        combine_kernel<<<2048, 256, 0, stream>>>(y0buf, y1buf, tpair, cw, out);
    } else {
        router_kernel<<<NT, 64, 0, stream>>>(x, rw, counts, sel, cw, nullptr);
        prefix_kernel<<<1, 1, 0, stream>>>(counts, cursor, offsets);
        scatter_kernel<<<NT / 256, 256, 0, stream>>>(sel, cw, offsets, cursor, ptok, pcw, tpair);
        hipMemsetAsync(d_out, 0, (size_t)out_size * sizeof(float), stream);
        gemm1_kernel<<<dim3(NH / 128, 32, NE), 256, 0, stream>>>(x, w1, w3, counts, offsets, ptok, hbuf);
        gemm2_kernel<<<dim3(ND / 128, 32, NE), 256, 0, stream>>>(hbuf, w2, counts, offsets, ptok, pcw, out);
    }
}